// Round 5
// baseline (327.589 us; speedup 1.0000x reference)
//
#include <hip/hip_runtime.h>
#include <math.h>

// Problem constants
#define NB    8192          // N
#define FEAT  255
#define HID   64
#define TOPK  6000
#define POSTK 300
#define BINS  8192          // 13-bit sortable-float key bins (sign+8exp+4mant)
#define BSHIFT 19           // 32-13
#define CAP   131072        // candidate buffer capacity
#define CAPLIM 49152        // target upper bound on estimated candidate count
#define SLACK 1             // bins below bstar (bf16-mfma vs f64 err 0.03 << bin 0.5)
#define TSEL  500           // sampled cnt_ge target (1/16 col sample: true>=6000 at ~6 sigma)
#define SAMPF 16            // sample factor (512 of 8192 cols)
#define JSLICES 128         // j-dimension parallelism for rank counting
#define LCAP  2048          // per-block LDS candidate buffer (overflow -> direct atomic)
#define NMS_ICH 64          // nms i-chunk per block

typedef __attribute__((ext_vector_type(8))) short bf16x8;
typedef __attribute__((ext_vector_type(4))) float f32x4;
typedef __attribute__((ext_vector_type(4))) double f64x4;

__device__ __forceinline__ unsigned binOf(float x) {
    unsigned u = __float_as_uint(x);
    u = (u & 0x80000000u) ? ~u : (u | 0x80000000u);   // sortable key (ascending)
    return u >> BSHIFT;
}

__device__ __forceinline__ unsigned short f2bf(float f) {   // RNE bf16 (finite inputs)
    unsigned u = __float_as_uint(f);
    return (unsigned short)((u + 0x7fffu + ((u >> 16) & 1u)) >> 16);
}

// ---------------------------------------------------------------------------
// K1: the two 255->64->64 MLPs via v_mfma_f64_16x16x4_f64 (R21). Block = 16
// rows, wave = (net, tj-pair); feat tile in LDS f32 stride-258, K padded
// 255->256 via zeroed LDS column + exec-masked tail B load. h (relu) kept
// in LDS f64 stride-65 for layer 2. Deterministic (~1e-15 rel err).
// ---------------------------------------------------------------------------
__global__ __launch_bounds__(256) void mlp_kernel(
    const float* __restrict__ feat,
    const float* __restrict__ W1s, const float* __restrict__ b1s,
    const float* __restrict__ W2s, const float* __restrict__ b2s,
    const float* __restrict__ W1o, const float* __restrict__ b1o,
    const float* __restrict__ W2o, const float* __restrict__ b2o,
    double* __restrict__ Xs64, double* __restrict__ Xo64,
    unsigned short* __restrict__ Xsb, unsigned short* __restrict__ Xob)
{
    __shared__ float  fl[16 * 258];       // feat tile, padded stride 258 (16.5 KB)
    __shared__ double hl[2][16][65];      // relu(h1), padded stride 65 (16.6 KB)

    int tid  = threadIdx.x;
    int lane = tid & 63;
    int w    = tid >> 6;
    int a16  = lane & 15;     // row (A) / col (B,D) within 16-tile
    int kq   = lane >> 4;     // k-quad 0..3
    int net  = w & 1;         // 0 = subject, 1 = object
    int p    = w >> 1;        // tj pair: cols [32p, 32p+32)
    int rbase = blockIdx.x * 16;

    // ---- stage feat tile: 16 rows x 255 f32, row-linear in global ----
    const float* fsrc = feat + (size_t)rbase * FEAT;
    for (int idx = tid; idx < 16 * FEAT; idx += 256) {
        int r = idx / FEAT;
        int k = idx - r * FEAT;
        fl[r * 258 + k] = fsrc[idx];
    }
    if (tid < 16) fl[tid * 258 + 255] = 0.0f;   // K-pad column
    __syncthreads();

    const float* W1 = net ? W1o : W1s;
    const float* B1 = net ? b1o : b1s;
    const float* W2 = net ? W2o : W2s;
    const float* B2 = net ? b2o : b2s;
    double*       X  = net ? Xo64 : Xs64;
    unsigned short* Xb = net ? Xob : Xsb;

    int c0 = (2 * p) * 16 + a16;
    int c1 = (2 * p + 1) * 16 + a16;

    // ---- layer 1: K=255 -> 63 full ksteps + masked tail ----
    f64x4 acc0 = {0, 0, 0, 0}, acc1 = {0, 0, 0, 0};
#pragma unroll 4
    for (int ks = 0; ks < 63; ++ks) {
        int k = ks * 4 + kq;
        double av = (double)fl[a16 * 258 + k];
        double b0 = (double)W1[k * HID + c0];
        double b1 = (double)W1[k * HID + c1];
        acc0 = __builtin_amdgcn_mfma_f64_16x16x4f64(av, b0, acc0, 0, 0, 0);
        acc1 = __builtin_amdgcn_mfma_f64_16x16x4f64(av, b1, acc1, 0, 0, 0);
    }
    {   // tail kstep: k = 252+kq; kq==3 is the pad lane (A=0, B exec-masked)
        int k = 252 + kq;
        double av = (double)fl[a16 * 258 + k];
        double b0 = 0.0, b1 = 0.0;
        if (k < FEAT) {
            b0 = (double)W1[k * HID + c0];
            b1 = (double)W1[k * HID + c1];
        }
        acc0 = __builtin_amdgcn_mfma_f64_16x16x4f64(av, b0, acc0, 0, 0, 0);
        acc1 = __builtin_amdgcn_mfma_f64_16x16x4f64(av, b1, acc1, 0, 0, 0);
    }

    // bias + relu -> hl  (D: col = c0/c1, row = kq*4 + i)
    {
        double bb0 = (double)B1[c0], bb1 = (double)B1[c1];
#pragma unroll
        for (int i = 0; i < 4; ++i) {
            int r = kq * 4 + i;
            double v0 = acc0[i] + bb0;
            double v1 = acc1[i] + bb1;
            hl[net][r][c0] = v0 > 0.0 ? v0 : 0.0;
            hl[net][r][c1] = v1 > 0.0 ? v1 : 0.0;
        }
    }
    __syncthreads();

    // ---- layer 2: K=64 -> 16 ksteps ----
    f64x4 x0 = {0, 0, 0, 0}, x1 = {0, 0, 0, 0};
#pragma unroll 4
    for (int ks = 0; ks < 16; ++ks) {
        int k = ks * 4 + kq;
        double av = hl[net][a16][k];
        double b0 = (double)W2[k * HID + c0];
        double b1 = (double)W2[k * HID + c1];
        x0 = __builtin_amdgcn_mfma_f64_16x16x4f64(av, b0, x0, 0, 0, 0);
        x1 = __builtin_amdgcn_mfma_f64_16x16x4f64(av, b1, x1, 0, 0, 0);
    }

    // bias + store f64 and bf16 views
    {
        double bb0 = (double)B2[c0], bb1 = (double)B2[c1];
#pragma unroll
        for (int i = 0; i < 4; ++i) {
            int r = kq * 4 + i;
            double v0 = x0[i] + bb0;
            double v1 = x1[i] + bb1;
            size_t o0 = (size_t)(rbase + r) * HID + c0;
            size_t o1 = (size_t)(rbase + r) * HID + c1;
            X[o0] = v0; X[o1] = v1;
            Xb[o0] = f2bf((float)v0);
            Xb[o1] = f2bf((float)v1);
        }
    }
}

// ---------------------------------------------------------------------------
// K2: histogram over a 1/16 column sample (cols 0..511) with fused
// threshold selection via last-block election on ctrl[3] (R23, verified).
// ---------------------------------------------------------------------------
__global__ __launch_bounds__(256) void mfma_hist(
    const unsigned short* __restrict__ Xsb, const unsigned short* __restrict__ Xob,
    unsigned* __restrict__ ghist, unsigned* __restrict__ ctrl)
{
    __shared__ unsigned hist[BINS];   // 32 KB (reused as staged ghist by winner)
    __shared__ unsigned csum[256];
    __shared__ bool win_s;
    int tid = threadIdx.x;
    for (int i = tid; i < BINS; i += 256) hist[i] = 0u;
    __syncthreads();

    int lane = tid & 63;
    int wave = tid >> 6;
    int quad = lane >> 4;
    int l16  = lane & 15;
    int r0 = blockIdx.y * 128 + (wave >> 1) * 64;
    int c0 = blockIdx.x * 128 + (wave & 1) * 64;   // gridDim.x = 4 -> cols 0..511

    f32x4 acc[4][4];
    bf16x8 afr[2][4], bfr[2][4];
#pragma unroll
    for (int kc = 0; kc < 2; ++kc)
#pragma unroll
        for (int t = 0; t < 4; ++t) {
            afr[kc][t] = *(const bf16x8*)(Xsb + (size_t)(r0 + t * 16 + l16) * HID + kc * 32 + quad * 8);
            bfr[kc][t] = *(const bf16x8*)(Xob + (size_t)(c0 + t * 16 + l16) * HID + kc * 32 + quad * 8);
        }
#pragma unroll
    for (int ti = 0; ti < 4; ++ti)
#pragma unroll
        for (int tj = 0; tj < 4; ++tj) acc[ti][tj] = (f32x4){0, 0, 0, 0};
#pragma unroll
    for (int kc = 0; kc < 2; ++kc)
#pragma unroll
        for (int ti = 0; ti < 4; ++ti)
#pragma unroll
            for (int tj = 0; tj < 4; ++tj)
                acc[ti][tj] = __builtin_amdgcn_mfma_f32_16x16x32_bf16(
                    afr[kc][ti], bfr[kc][tj], acc[ti][tj], 0, 0, 0);

#pragma unroll
    for (int ti = 0; ti < 4; ++ti)
#pragma unroll
        for (int tj = 0; tj < 4; ++tj)
#pragma unroll
            for (int i = 0; i < 4; ++i) {
                int r = r0 + ti * 16 + quad * 4 + i;
                int c = c0 + tj * 16 + l16;
                float v = acc[ti][tj][i];
                if (v > 0.0f && r != c)
                    atomicAdd(&hist[binOf(v)], 1u);
            }

    __syncthreads();
    for (int i = tid; i < BINS; i += 256) {
        unsigned h = hist[i];
        if (h) atomicAdd(&ghist[i], h);
    }

    // ---- last-block election: winner computes the threshold ----
    __syncthreads();
    if (tid == 0) {
        __threadfence();
        unsigned done = atomicAdd(&ctrl[3], 1u);
        win_s = (done == gridDim.x * gridDim.y - 1u);
    }
    __syncthreads();
    if (!win_s) return;

    for (int i = tid; i < BINS; i += 256)
        hist[i] = __hip_atomic_load(&ghist[i], __ATOMIC_RELAXED, __HIP_MEMORY_SCOPE_AGENT);
    __syncthreads();

    int base = tid * (BINS / 256);
    unsigned s = 0;
    for (int i = 0; i < BINS / 256; ++i) s += hist[base + i];
    csum[tid] = s;
    __syncthreads();
    if (tid == 0) {                       // suffix sums of chunk totals
        unsigned run = 0;
        for (int c = 255; c >= 0; --c) { run += csum[c]; csum[c] = run; }
    }
    __syncthreads();

    unsigned above = (tid == 255) ? 0u : csum[tid + 1];  // cnt_ge[chunk end]
    unsigned prev = above;
    for (int b = base + BINS / 256 - 1; b >= base; --b) {
        unsigned cur = prev + hist[b];
        if (cur >= TSEL && prev < TSEL) {
            unsigned bstar = (unsigned)b;
            unsigned bt = bstar >= SLACK ? bstar - SLACK : 0;
            unsigned cnt = cur;
            for (unsigned bb = bstar; bb-- > bt;) cnt += hist[bb];
            while ((unsigned)SAMPF * cnt > CAPLIM && bt < bstar) { cnt -= hist[bt]; bt++; }
            ctrl[1] = bt;
            unsigned key = bt << BSHIFT;
            unsigned fbits;
            if (key == 0u) fbits = 0xff800000u;               // -inf: all pass
            else fbits = (key & 0x80000000u) ? (key ^ 0x80000000u) : ~key;
            ctrl[2] = fbits;
            break;
        }
        prev = cur;
    }
}

// ---------------------------------------------------------------------------
// K4 (R24): filter + INLINE REFINE. The filter block owns its candidates in
// lbuf + gbase, so its 4 waves do the 64-lane f64 dot + butterfly reduce
// right here (identical summation order -> bit-identical cval vs the old
// refine_kernel) and zero rank[g]. Kills the 2048-block refine dispatch and
// its cidx re-read. Overflow path (>LCAP, statistically unreachable)
// refines scalar in-lane. Same candidate set; chunk order free.
// ---------------------------------------------------------------------------
__global__ __launch_bounds__(256) void mfma_filter(
    const unsigned short* __restrict__ Xsb, const unsigned short* __restrict__ Xob,
    unsigned* __restrict__ ctrl, unsigned* __restrict__ cidx,
    const double* __restrict__ Xs64, const double* __restrict__ Xo64,
    double* __restrict__ cval, unsigned* __restrict__ rank)
{
    __shared__ unsigned lcnt;
    __shared__ unsigned gbase;
    __shared__ unsigned lbuf[LCAP];   // 8 KB
    float vt = __uint_as_float(ctrl[2]);
    int tid = threadIdx.x;
    if (tid == 0) lcnt = 0;

    int lane = tid & 63;
    int wave = tid >> 6;
    int quad = lane >> 4;
    int l16  = lane & 15;
    int r0 = blockIdx.y * 128 + (wave >> 1) * 64;
    int cb = blockIdx.x * 256 + (wave & 1) * 64;

    // A fragments: loaded once, reused across all 8 column chunks
    bf16x8 afr[2][4];
#pragma unroll
    for (int kc = 0; kc < 2; ++kc)
#pragma unroll
        for (int t = 0; t < 4; ++t)
            afr[kc][t] = *(const bf16x8*)(Xsb + (size_t)(r0 + t * 16 + l16) * HID + kc * 32 + quad * 8);

    // prefetch chunk 0 and chunk 1's B fragments (pipeline stages b0,b1)
    bf16x8 b0[2], b1[2];
    {
        int col0 = cb + l16;           // q=0: ct=0, tj=0
        int col1 = cb + 16 + l16;      // q=1: ct=0, tj=1
#pragma unroll
        for (int kc = 0; kc < 2; ++kc) {
            b0[kc] = *(const bf16x8*)(Xob + (size_t)col0 * HID + kc * 32 + quad * 8);
            b1[kc] = *(const bf16x8*)(Xob + (size_t)col1 * HID + kc * 32 + quad * 8);
        }
    }

    __syncthreads();   // lcnt=0 visible

#pragma unroll
    for (int q = 0; q < 8; ++q) {
        int ct = q >> 2, tj = q & 3;
        int c0 = cb + ct * 128;
        int cj = c0 + tj * 16 + l16;
        bool nodiag = (r0 != c0);

        // prefetch chunk q+2's B fragments
        bf16x8 b2[2];
        if (q < 6) {
            int q2 = q + 2;
            int col2 = cb + (q2 >> 2) * 128 + (q2 & 3) * 16 + l16;
#pragma unroll
            for (int kc = 0; kc < 2; ++kc)
                b2[kc] = *(const bf16x8*)(Xob + (size_t)col2 * HID + kc * 32 + quad * 8);
        }

        f32x4 acc[4];
#pragma unroll
        for (int ti = 0; ti < 4; ++ti) acc[ti] = (f32x4){0, 0, 0, 0};
#pragma unroll
        for (int kc = 0; kc < 2; ++kc)
#pragma unroll
            for (int ti = 0; ti < 4; ++ti)
                acc[ti] = __builtin_amdgcn_mfma_f32_16x16x32_bf16(
                    afr[kc][ti], b0[kc], acc[ti], 0, 0, 0);

        // hit mask (diagonal folded in); skip whole epilogue if wave-empty
        unsigned hm = 0u;
#pragma unroll
        for (int ti = 0; ti < 4; ++ti)
#pragma unroll
            for (int i = 0; i < 4; ++i) {
                bool hit = acc[ti][i] >= vt;
                if (!nodiag) {
                    int r = r0 + ti * 16 + quad * 4 + i;
                    hit = hit && (r != cj);
                }
                hm |= hit ? (1u << (ti * 4 + i)) : 0u;
            }

        if (__any(hm != 0u)) {
#pragma unroll
            for (int ti = 0; ti < 4; ++ti)
#pragma unroll
                for (int i = 0; i < 4; ++i) {
                    if (hm & (1u << (ti * 4 + i))) {
                        int r = r0 + ti * 16 + quad * 4 + i;
                        unsigned rc = (unsigned)r * (unsigned)NB + (unsigned)cj;
                        unsigned p = atomicAdd(&lcnt, 1u);
                        if (p < LCAP) {
                            lbuf[p] = rc;
                        } else {
                            unsigned g = atomicAdd(&ctrl[0], 1u);
                            if (g < CAP) {
                                cidx[g] = rc;
                                // inline scalar refine (unreachable in practice)
                                const double* xr = Xs64 + (size_t)r * HID;
                                const double* xc = Xo64 + (size_t)cj * HID;
                                double a64 = 0.0;
                                for (int k = 0; k < HID; ++k) a64 += xr[k] * xc[k];
                                cval[g] = a64;
                                rank[g] = 0u;
                            }
                        }
                    }
                }
        }

        // rotate pipeline (full unroll -> register renames, no copies)
        if (q < 6) {
            b0[0] = b1[0]; b0[1] = b1[1];
            b1[0] = b2[0]; b1[1] = b2[1];
        } else if (q == 6) {
            b0[0] = b1[0]; b0[1] = b1[1];
        }
    }

    __syncthreads();
    unsigned n = lcnt; if (n > LCAP) n = LCAP;
    if (tid == 0 && n) gbase = atomicAdd(&ctrl[0], n);
    __syncthreads();
    for (unsigned i = tid; i < n; i += 256u) {
        unsigned p = gbase + i;
        if (p < CAP) cidx[p] = lbuf[i];
    }

    // ---- inline refine: one wave per candidate (butterfly order identical
    // to the old refine_kernel -> bit-identical cval); also zeroes rank[g].
    for (unsigned i = (unsigned)wave; i < n; i += 4u) {
        unsigned g = gbase + i;
        if (g < CAP) {
            unsigned rc = lbuf[i];
            unsigned r = rc >> 13, c = rc & (NB - 1u);
            double pr = Xs64[(size_t)r * HID + lane] * Xo64[(size_t)c * HID + lane];
#pragma unroll
            for (int s = 32; s > 0; s >>= 1) pr += __shfl_xor(pr, s);
            if (lane == 0) { cval[g] = pr; rank[g] = 0u; }
        }
    }
}

// ---------------------------------------------------------------------------
// K5a (R24): rank-by-counting + fused scatter/NMS-prep via last-block
// election on ctrl[4]. Winner reads rank[] with agent-scope loads (atomics
// resolve at the device-coherent point; plain loads could hit a stale
// per-XCD L2). cval/cidx/rois are plain reads (written >=1 dispatch ago).
// ---------------------------------------------------------------------------
__global__ __launch_bounds__(256) void rank_count(
    unsigned* __restrict__ ctrl,
    const double* __restrict__ cval, const unsigned* __restrict__ cidx,
    unsigned* __restrict__ rank, const float* __restrict__ rois,
    double* __restrict__ sval, unsigned* __restrict__ sidx,
    double* __restrict__ ub)
{
    unsigned M = ctrl[0];
    if (M > CAP) M = CAP;

    unsigned slice = blockIdx.y;
    unsigned jbeg = (unsigned)(((unsigned long long)slice * M) / JSLICES);
    unsigned jend = (unsigned)(((unsigned long long)(slice + 1) * M) / JSLICES);

    __shared__ double  lv[256];
    __shared__ unsigned li[256];
    __shared__ bool win_s;

    for (unsigned itile = blockIdx.x; itile * 1024u < M; itile += gridDim.x) {
        unsigned i0 = itile * 1024u + threadIdx.x;   // + k*256 per slot
        double v[4];
        unsigned id[4];
        unsigned cnt[4] = {0, 0, 0, 0};
#pragma unroll
        for (int k = 0; k < 4; ++k) {
            unsigned idx = i0 + (unsigned)k * 256u;
            bool a = idx < M;
            v[k]  = a ? cval[idx] : 0.0;
            id[k] = a ? cidx[idx] : 0u;
        }

        for (unsigned base = jbeg; base < jend; base += 256u) {
            unsigned j = base + threadIdx.x;
            if (j < jend) { lv[threadIdx.x] = cval[j]; li[threadIdx.x] = cidx[j]; }
            __syncthreads();
            unsigned lim = jend - base; if (lim > 256u) lim = 256u;
            for (unsigned e = 0; e < lim; ++e) {
                double ev = lv[e];
                unsigned ei = li[e];
#pragma unroll
                for (int k = 0; k < 4; ++k)
                    cnt[k] += (ev > v[k]) || (ev == v[k] && ei < id[k]);
            }
            __syncthreads();
        }
#pragma unroll
        for (int k = 0; k < 4; ++k) {
            unsigned idx = i0 + (unsigned)k * 256u;
            if (idx < M && cnt[k]) atomicAdd(&rank[idx], cnt[k]);
        }
    }

    // ---- last-block election: winner scatters + builds NMS boxes ----
    __syncthreads();
    if (threadIdx.x == 0) {
        __threadfence();
        unsigned done = atomicAdd(&ctrl[4], 1u);
        win_s = (done == gridDim.x * gridDim.y - 1u);
    }
    __syncthreads();
    if (!win_s) return;

    for (unsigned t = threadIdx.x; t < M; t += 256u) {
        unsigned rk = __hip_atomic_load(&rank[t], __ATOMIC_RELAXED, __HIP_MEMORY_SCOPE_AGENT);
        if (rk < TOPK) {
            unsigned id = cidx[t];
            sval[rk] = cval[t];
            sidx[rk] = id;
            unsigned s = id >> 13, o = id & (NB - 1);
            const float* bs = rois + (size_t)s * 5;
            const float* bo = rois + (size_t)o * 5;
            double x1 = fmin((double)bs[1], (double)bo[1]);
            double y1 = fmin((double)bs[2], (double)bo[2]);
            double x2 = fmax((double)bs[3], (double)bo[3]);
            double y2 = fmax((double)bs[4], (double)bo[4]);
            double area = (x2 - x1) * (y2 - y1);
            double* u = ub + (size_t)rk * 5;
            u[0] = x1; u[1] = y1; u[2] = x2; u[3] = y2; u[4] = 0.7 * area;
        }
    }
}

// ---------------------------------------------------------------------------
// K7 (R24): NMS + fused finalize via last-block election on ctrl[5].
// sup[] writes upgraded to agent-scope atomic stores (device-coherent) so
// the winner's agent-scope reads are valid across XCDs. All blocks reach
// the election (early-outs became guards). Winner = 256-thread variant of
// the old finalize: stable partition of where(sup,-1,score), top-300 out.
// ---------------------------------------------------------------------------
__global__ __launch_bounds__(256) void nms_kernel(
    const double* __restrict__ ub, unsigned* sup, unsigned* __restrict__ ctrl,
    const double* __restrict__ sval, const unsigned* __restrict__ sidx,
    float* __restrict__ out)
{
    __shared__ double L[NMS_ICH][5];
    __shared__ bool win_s;
    int jb = blockIdx.x;              // j-tile: 256 j's
    int ic = blockIdx.y;              // i-chunk: 64 i's
    int ibase = ic * NMS_ICH;
    int tid = threadIdx.x;

    bool blk_active = (ibase < TOPK) && (ibase < jb * 256 + 255);
    if (blk_active) {
        int icount = TOPK - ibase; if (icount > NMS_ICH) icount = NMS_ICH;
        for (int q = tid; q < icount * 5; q += 256)
            L[q / 5][q % 5] = ub[(size_t)ibase * 5 + q];
        __syncthreads();

        int j = jb * 256 + tid;
        if (j < TOPK) {
            int lim = j - ibase; if (lim > icount) lim = icount;  // i < j
            if (lim > 0) {
                const double* u = ub + (size_t)j * 5;
                double x1 = u[0], y1 = u[1], x2 = u[2], y2 = u[3], pa = u[4];
                bool flag = false;
                for (int e = 0; e < lim; ++e) {
                    double ix1 = fmax(L[e][0], x1);
                    double iy1 = fmax(L[e][1], y1);
                    double ix2 = fmin(L[e][2], x2);
                    double iy2 = fmin(L[e][3], y2);
                    double iw = ix2 - ix1; iw = iw > 0.0 ? iw : 0.0;
                    double ih = iy2 - iy1; ih = ih > 0.0 ? ih : 0.0;
                    flag |= (1.7 * (iw * ih) > pa + L[e][4] + 7e-9);
                }
                if (flag)
                    __hip_atomic_store(&sup[j], 1u, __ATOMIC_RELAXED, __HIP_MEMORY_SCOPE_AGENT);
            }
        }
    }

    // ---- last-block election: winner runs finalize (256-thread) ----
    __syncthreads();
    if (tid == 0) {
        __threadfence();
        unsigned done = atomicAdd(&ctrl[5], 1u);
        win_s = (done == gridDim.x * gridDim.y - 1u);
    }
    __syncthreads();
    if (!win_s) return;

    __shared__ unsigned wsum[4];
    __shared__ unsigned red[4];
    __shared__ unsigned bases[2];   // running {unsup, sup} counts
    __shared__ unsigned totalu_s;
    int lane = tid & 63;
    int w    = tid >> 6;

    unsigned s = 0;
    for (int i = tid; i < TOPK; i += 256)
        s += (__hip_atomic_load(&sup[i], __ATOMIC_RELAXED, __HIP_MEMORY_SCOPE_AGENT) == 0u);
#pragma unroll
    for (int st = 32; st > 0; st >>= 1) s += __shfl_down(s, st);
    if (lane == 0) red[w] = s;
    __syncthreads();
    if (tid == 0) {
        unsigned tot = red[0] + red[1] + red[2] + red[3];
        totalu_s = tot; bases[0] = 0; bases[1] = 0;
    }
    __syncthreads();
    unsigned totalu = totalu_s;

    for (int c = 0; c < (TOPK + 255) / 256; ++c) {
        int idx = c * 256 + tid;
        int valid = TOPK - c * 256; if (valid > 256) valid = 256;
        unsigned f = (idx < TOPK &&
                      __hip_atomic_load(&sup[idx], __ATOMIC_RELAXED, __HIP_MEMORY_SCOPE_AGENT) == 0u)
                     ? 1u : 0u;
        unsigned long long m = __ballot(f != 0u);
        if (lane == 0) wsum[w] = (unsigned)__popcll(m);
        __syncthreads();
        unsigned wbase = 0, ctot = 0;
#pragma unroll
        for (int i = 0; i < 4; ++i) {
            unsigned v = wsum[i];
            if (i < w) wbase += v;
            ctot += v;
        }
        unsigned e = wbase + (unsigned)__popcll(m & ((1ull << lane) - 1ull));
        if (idx < TOPK) {
            unsigned pos = f ? (bases[0] + e)
                             : (totalu + bases[1] + (unsigned)tid - e);
            if (pos < POSTK) {
                unsigned id = sidx[idx];
                unsigned sb = id >> 13, ob = id & (NB - 1);
                out[2 * pos]     = (float)sb;
                out[2 * pos + 1] = (float)ob;
                double sg = f ? 1.0 / (1.0 + exp(-sval[idx])) : -1.0;
                out[2 * POSTK + pos] = (float)sg;
            }
        }
        __syncthreads();
        if (tid == 0) {
            bases[0] += ctot;
            bases[1] += (unsigned)valid - ctot;
        }
        __syncthreads();
    }
}

// ---------------------------------------------------------------------------
extern "C" void kernel_launch(void* const* d_in, const int* in_sizes, int n_in,
                              void* d_out, int out_size, void* d_ws, size_t ws_size,
                              hipStream_t stream)
{
    const float* rois = (const float*)d_in[0];
    const float* feat = (const float*)d_in[1];
    const float* W1s  = (const float*)d_in[2];
    const float* b1s  = (const float*)d_in[3];
    const float* W2s  = (const float*)d_in[4];
    const float* b2s  = (const float*)d_in[5];
    const float* W1o  = (const float*)d_in[6];
    const float* b1o  = (const float*)d_in[7];
    const float* W2o  = (const float*)d_in[8];
    const float* b2o  = (const float*)d_in[9];

    char* ws = (char*)d_ws;
    size_t off = 0;
    auto alloc = [&](size_t bytes) -> void* {
        off = (off + 255) & ~(size_t)255;
        void* p = ws + off;
        off += bytes;
        return p;
    };

    // zeroed region first (rank moved out: filter zeroes rank[g] per cand)
    unsigned* ghist = (unsigned*)alloc((size_t)BINS * 4);     // histogram
    unsigned* ctrl  = (unsigned*)alloc(256);                  // [0]=count [1]=bin [2]=thr [3..5]=elections
    unsigned* sup   = (unsigned*)alloc((size_t)6144 * 4);     // suppression flags
    size_t zero_bytes = off;

    unsigned* rank  = (unsigned*)alloc((size_t)CAP * 4);      // candidate ranks
    double* Xs64 = (double*)alloc((size_t)NB * HID * 8);
    double* Xo64 = (double*)alloc((size_t)NB * HID * 8);
    unsigned short* Xsb = (unsigned short*)alloc((size_t)NB * HID * 2);
    unsigned short* Xob = (unsigned short*)alloc((size_t)NB * HID * 2);
    double* cval = (double*)alloc((size_t)CAP * 8);
    unsigned* cidx = (unsigned*)alloc((size_t)CAP * 4);
    double* svalv = (double*)alloc((size_t)TOPK * 8);
    unsigned* sidxv = (unsigned*)alloc((size_t)TOPK * 4);
    double* ub   = (double*)alloc((size_t)TOPK * 5 * 8);

    (void)hipMemsetAsync(d_ws, 0, zero_bytes, stream);

    mlp_kernel<<<NB / 16, 256, 0, stream>>>(feat, W1s, b1s, W2s, b2s,
                                            W1o, b1o, W2o, b2o,
                                            Xs64, Xo64, Xsb, Xob);
    mfma_hist<<<dim3(4, 64), 256, 0, stream>>>(Xsb, Xob, ghist, ctrl);
    mfma_filter<<<dim3(32, 64), 256, 0, stream>>>(Xsb, Xob, ctrl, cidx,
                                                  Xs64, Xo64, cval, rank);
    rank_count<<<dim3(16, JSLICES), 256, 0, stream>>>(ctrl, cval, cidx, rank,
                                                      rois, svalv, sidxv, ub);
    nms_kernel<<<dim3((TOPK + 255) / 256, (TOPK + NMS_ICH - 1) / NMS_ICH), 256, 0, stream>>>(
        ub, sup, ctrl, svalv, sidxv, (float*)d_out);
}

// Round 6
// 222.126 us; speedup vs baseline: 1.4748x; 1.4748x over previous
//
#include <hip/hip_runtime.h>
#include <math.h>

// Problem constants
#define NB    8192          // N
#define FEAT  255
#define HID   64
#define TOPK  6000
#define POSTK 300
#define BINS  8192          // 13-bit sortable-float key bins (sign+8exp+4mant)
#define BSHIFT 19           // 32-13
#define CAP   131072        // candidate buffer capacity
#define CAPLIM 16384        // R25: target upper bound on candidate count (was 49152;
                            // rank_count is O(M^2), refine O(M); top-6000 coverage is
                            // guaranteed by the bt<=bstar walk bound, not CAPLIM)
#define SLACK 1             // bins below bstar (bf16-mfma vs f64 err 0.03 << bin 0.5)
#define TSEL  500           // sampled cnt_ge target (1/16 col sample: true>=6000 at ~6 sigma)
#define SAMPF 16            // sample factor (512 of 8192 cols)
#define JSLICES 128         // j-dimension parallelism for rank counting
#define LCAP  2048          // per-block LDS candidate buffer (overflow -> direct atomic)
#define NMS_ICH 64          // nms i-chunk per block

typedef __attribute__((ext_vector_type(8))) short bf16x8;
typedef __attribute__((ext_vector_type(4))) float f32x4;
typedef __attribute__((ext_vector_type(4))) double f64x4;

__device__ __forceinline__ unsigned binOf(float x) {
    unsigned u = __float_as_uint(x);
    u = (u & 0x80000000u) ? ~u : (u | 0x80000000u);   // sortable key (ascending)
    return u >> BSHIFT;
}

__device__ __forceinline__ unsigned short f2bf(float f) {   // RNE bf16 (finite inputs)
    unsigned u = __float_as_uint(f);
    return (unsigned short)((u + 0x7fffu + ((u >> 16) & 1u)) >> 16);
}

// ---------------------------------------------------------------------------
// K1: the two 255->64->64 MLPs via v_mfma_f64_16x16x4_f64 (R21). Block = 16
// rows, wave = (net, tj-pair); feat tile in LDS f32 stride-258, K padded
// 255->256 via zeroed LDS column + exec-masked tail B load. h (relu) kept
// in LDS f64 stride-65 for layer 2. Deterministic (~1e-15 rel err).
// R25 note: election-fusing O(M) tails into one block costs 10-30x the
// ~2us dispatch overhead (R24 post-mortem: rank_count 43->112us). Only
// fuse O(BINS)-small tails (hist threshold).
// ---------------------------------------------------------------------------
__global__ __launch_bounds__(256) void mlp_kernel(
    const float* __restrict__ feat,
    const float* __restrict__ W1s, const float* __restrict__ b1s,
    const float* __restrict__ W2s, const float* __restrict__ b2s,
    const float* __restrict__ W1o, const float* __restrict__ b1o,
    const float* __restrict__ W2o, const float* __restrict__ b2o,
    double* __restrict__ Xs64, double* __restrict__ Xo64,
    unsigned short* __restrict__ Xsb, unsigned short* __restrict__ Xob)
{
    __shared__ float  fl[16 * 258];       // feat tile, padded stride 258 (16.5 KB)
    __shared__ double hl[2][16][65];      // relu(h1), padded stride 65 (16.6 KB)

    int tid  = threadIdx.x;
    int lane = tid & 63;
    int w    = tid >> 6;
    int a16  = lane & 15;     // row (A) / col (B,D) within 16-tile
    int kq   = lane >> 4;     // k-quad 0..3
    int net  = w & 1;         // 0 = subject, 1 = object
    int p    = w >> 1;        // tj pair: cols [32p, 32p+32)
    int rbase = blockIdx.x * 16;

    // ---- stage feat tile: 16 rows x 255 f32, row-linear in global ----
    const float* fsrc = feat + (size_t)rbase * FEAT;
    for (int idx = tid; idx < 16 * FEAT; idx += 256) {
        int r = idx / FEAT;
        int k = idx - r * FEAT;
        fl[r * 258 + k] = fsrc[idx];
    }
    if (tid < 16) fl[tid * 258 + 255] = 0.0f;   // K-pad column
    __syncthreads();

    const float* W1 = net ? W1o : W1s;
    const float* B1 = net ? b1o : b1s;
    const float* W2 = net ? W2o : W2s;
    const float* B2 = net ? b2o : b2s;
    double*       X  = net ? Xo64 : Xs64;
    unsigned short* Xb = net ? Xob : Xsb;

    int c0 = (2 * p) * 16 + a16;
    int c1 = (2 * p + 1) * 16 + a16;

    // ---- layer 1: K=255 -> 63 full ksteps + masked tail ----
    f64x4 acc0 = {0, 0, 0, 0}, acc1 = {0, 0, 0, 0};
#pragma unroll 4
    for (int ks = 0; ks < 63; ++ks) {
        int k = ks * 4 + kq;
        double av = (double)fl[a16 * 258 + k];
        double b0 = (double)W1[k * HID + c0];
        double b1 = (double)W1[k * HID + c1];
        acc0 = __builtin_amdgcn_mfma_f64_16x16x4f64(av, b0, acc0, 0, 0, 0);
        acc1 = __builtin_amdgcn_mfma_f64_16x16x4f64(av, b1, acc1, 0, 0, 0);
    }
    {   // tail kstep: k = 252+kq; kq==3 is the pad lane (A=0, B exec-masked)
        int k = 252 + kq;
        double av = (double)fl[a16 * 258 + k];
        double b0 = 0.0, b1 = 0.0;
        if (k < FEAT) {
            b0 = (double)W1[k * HID + c0];
            b1 = (double)W1[k * HID + c1];
        }
        acc0 = __builtin_amdgcn_mfma_f64_16x16x4f64(av, b0, acc0, 0, 0, 0);
        acc1 = __builtin_amdgcn_mfma_f64_16x16x4f64(av, b1, acc1, 0, 0, 0);
    }

    // bias + relu -> hl  (D: col = c0/c1, row = kq*4 + i)
    {
        double bb0 = (double)B1[c0], bb1 = (double)B1[c1];
#pragma unroll
        for (int i = 0; i < 4; ++i) {
            int r = kq * 4 + i;
            double v0 = acc0[i] + bb0;
            double v1 = acc1[i] + bb1;
            hl[net][r][c0] = v0 > 0.0 ? v0 : 0.0;
            hl[net][r][c1] = v1 > 0.0 ? v1 : 0.0;
        }
    }
    __syncthreads();

    // ---- layer 2: K=64 -> 16 ksteps ----
    f64x4 x0 = {0, 0, 0, 0}, x1 = {0, 0, 0, 0};
#pragma unroll 4
    for (int ks = 0; ks < 16; ++ks) {
        int k = ks * 4 + kq;
        double av = hl[net][a16][k];
        double b0 = (double)W2[k * HID + c0];
        double b1 = (double)W2[k * HID + c1];
        x0 = __builtin_amdgcn_mfma_f64_16x16x4f64(av, b0, x0, 0, 0, 0);
        x1 = __builtin_amdgcn_mfma_f64_16x16x4f64(av, b1, x1, 0, 0, 0);
    }

    // bias + store f64 and bf16 views
    {
        double bb0 = (double)B2[c0], bb1 = (double)B2[c1];
#pragma unroll
        for (int i = 0; i < 4; ++i) {
            int r = kq * 4 + i;
            double v0 = x0[i] + bb0;
            double v1 = x1[i] + bb1;
            size_t o0 = (size_t)(rbase + r) * HID + c0;
            size_t o1 = (size_t)(rbase + r) * HID + c1;
            X[o0] = v0; X[o1] = v1;
            Xb[o0] = f2bf((float)v0);
            Xb[o1] = f2bf((float)v1);
        }
    }
}

// ---------------------------------------------------------------------------
// K2: histogram over a 1/16 column sample (cols 0..511) with fused
// threshold selection via last-block election on ctrl[3] (R23, verified:
// the fused tail is O(BINS)=8K, small enough to serialize).
// ---------------------------------------------------------------------------
__global__ __launch_bounds__(256) void mfma_hist(
    const unsigned short* __restrict__ Xsb, const unsigned short* __restrict__ Xob,
    unsigned* __restrict__ ghist, unsigned* __restrict__ ctrl)
{
    __shared__ unsigned hist[BINS];   // 32 KB (reused as staged ghist by winner)
    __shared__ unsigned csum[256];
    __shared__ bool win_s;
    int tid = threadIdx.x;
    for (int i = tid; i < BINS; i += 256) hist[i] = 0u;
    __syncthreads();

    int lane = tid & 63;
    int wave = tid >> 6;
    int quad = lane >> 4;
    int l16  = lane & 15;
    int r0 = blockIdx.y * 128 + (wave >> 1) * 64;
    int c0 = blockIdx.x * 128 + (wave & 1) * 64;   // gridDim.x = 4 -> cols 0..511

    f32x4 acc[4][4];
    bf16x8 afr[2][4], bfr[2][4];
#pragma unroll
    for (int kc = 0; kc < 2; ++kc)
#pragma unroll
        for (int t = 0; t < 4; ++t) {
            afr[kc][t] = *(const bf16x8*)(Xsb + (size_t)(r0 + t * 16 + l16) * HID + kc * 32 + quad * 8);
            bfr[kc][t] = *(const bf16x8*)(Xob + (size_t)(c0 + t * 16 + l16) * HID + kc * 32 + quad * 8);
        }
#pragma unroll
    for (int ti = 0; ti < 4; ++ti)
#pragma unroll
        for (int tj = 0; tj < 4; ++tj) acc[ti][tj] = (f32x4){0, 0, 0, 0};
#pragma unroll
    for (int kc = 0; kc < 2; ++kc)
#pragma unroll
        for (int ti = 0; ti < 4; ++ti)
#pragma unroll
            for (int tj = 0; tj < 4; ++tj)
                acc[ti][tj] = __builtin_amdgcn_mfma_f32_16x16x32_bf16(
                    afr[kc][ti], bfr[kc][tj], acc[ti][tj], 0, 0, 0);

#pragma unroll
    for (int ti = 0; ti < 4; ++ti)
#pragma unroll
        for (int tj = 0; tj < 4; ++tj)
#pragma unroll
            for (int i = 0; i < 4; ++i) {
                int r = r0 + ti * 16 + quad * 4 + i;
                int c = c0 + tj * 16 + l16;
                float v = acc[ti][tj][i];
                if (v > 0.0f && r != c)
                    atomicAdd(&hist[binOf(v)], 1u);
            }

    __syncthreads();
    for (int i = tid; i < BINS; i += 256) {
        unsigned h = hist[i];
        if (h) atomicAdd(&ghist[i], h);
    }

    // ---- last-block election: winner computes the threshold ----
    __syncthreads();
    if (tid == 0) {
        __threadfence();
        unsigned done = atomicAdd(&ctrl[3], 1u);
        win_s = (done == gridDim.x * gridDim.y - 1u);
    }
    __syncthreads();
    if (!win_s) return;

    for (int i = tid; i < BINS; i += 256)
        hist[i] = __hip_atomic_load(&ghist[i], __ATOMIC_RELAXED, __HIP_MEMORY_SCOPE_AGENT);
    __syncthreads();

    int base = tid * (BINS / 256);
    unsigned s = 0;
    for (int i = 0; i < BINS / 256; ++i) s += hist[base + i];
    csum[tid] = s;
    __syncthreads();
    if (tid == 0) {                       // suffix sums of chunk totals
        unsigned run = 0;
        for (int c = 255; c >= 0; --c) { run += csum[c]; csum[c] = run; }
    }
    __syncthreads();

    unsigned above = (tid == 255) ? 0u : csum[tid + 1];  // cnt_ge[chunk end]
    unsigned prev = above;
    for (int b = base + BINS / 256 - 1; b >= base; --b) {
        unsigned cur = prev + hist[b];
        if (cur >= TSEL && prev < TSEL) {
            unsigned bstar = (unsigned)b;
            unsigned bt = bstar >= SLACK ? bstar - SLACK : 0;
            unsigned cnt = cur;
            for (unsigned bb = bstar; bb-- > bt;) cnt += hist[bb];
            while ((unsigned)SAMPF * cnt > CAPLIM && bt < bstar) { cnt -= hist[bt]; bt++; }
            ctrl[1] = bt;
            unsigned key = bt << BSHIFT;
            unsigned fbits;
            if (key == 0u) fbits = 0xff800000u;               // -inf: all pass
            else fbits = (key & 0x80000000u) ? (key ^ 0x80000000u) : ~key;
            ctrl[2] = fbits;
            break;
        }
        prev = cur;
    }
}

// ---------------------------------------------------------------------------
// K4: filter pass, 128x256 tile/block, chunked 16-AGPR accumulator, dist-2
// B prefetch, hit-mask fast path (skip atomic epilogue when wave-empty).
// Same candidate set; chunk order free. (R3-verified structure.)
// ---------------------------------------------------------------------------
__global__ __launch_bounds__(256) void mfma_filter(
    const unsigned short* __restrict__ Xsb, const unsigned short* __restrict__ Xob,
    unsigned* __restrict__ ctrl, unsigned* __restrict__ cidx)
{
    __shared__ unsigned lcnt;
    __shared__ unsigned gbase;
    __shared__ unsigned lbuf[LCAP];   // 8 KB
    float vt = __uint_as_float(ctrl[2]);
    int tid = threadIdx.x;
    if (tid == 0) lcnt = 0;

    int lane = tid & 63;
    int wave = tid >> 6;
    int quad = lane >> 4;
    int l16  = lane & 15;
    int r0 = blockIdx.y * 128 + (wave >> 1) * 64;
    int cb = blockIdx.x * 256 + (wave & 1) * 64;

    // A fragments: loaded once, reused across all 8 column chunks
    bf16x8 afr[2][4];
#pragma unroll
    for (int kc = 0; kc < 2; ++kc)
#pragma unroll
        for (int t = 0; t < 4; ++t)
            afr[kc][t] = *(const bf16x8*)(Xsb + (size_t)(r0 + t * 16 + l16) * HID + kc * 32 + quad * 8);

    // prefetch chunk 0 and chunk 1's B fragments (pipeline stages b0,b1)
    bf16x8 b0[2], b1[2];
    {
        int col0 = cb + l16;           // q=0: ct=0, tj=0
        int col1 = cb + 16 + l16;      // q=1: ct=0, tj=1
#pragma unroll
        for (int kc = 0; kc < 2; ++kc) {
            b0[kc] = *(const bf16x8*)(Xob + (size_t)col0 * HID + kc * 32 + quad * 8);
            b1[kc] = *(const bf16x8*)(Xob + (size_t)col1 * HID + kc * 32 + quad * 8);
        }
    }

    __syncthreads();   // lcnt=0 visible

#pragma unroll
    for (int q = 0; q < 8; ++q) {
        int ct = q >> 2, tj = q & 3;
        int c0 = cb + ct * 128;
        int cj = c0 + tj * 16 + l16;
        bool nodiag = (r0 != c0);

        // prefetch chunk q+2's B fragments
        bf16x8 b2[2];
        if (q < 6) {
            int q2 = q + 2;
            int col2 = cb + (q2 >> 2) * 128 + (q2 & 3) * 16 + l16;
#pragma unroll
            for (int kc = 0; kc < 2; ++kc)
                b2[kc] = *(const bf16x8*)(Xob + (size_t)col2 * HID + kc * 32 + quad * 8);
        }

        f32x4 acc[4];
#pragma unroll
        for (int ti = 0; ti < 4; ++ti) acc[ti] = (f32x4){0, 0, 0, 0};
#pragma unroll
        for (int kc = 0; kc < 2; ++kc)
#pragma unroll
            for (int ti = 0; ti < 4; ++ti)
                acc[ti] = __builtin_amdgcn_mfma_f32_16x16x32_bf16(
                    afr[kc][ti], b0[kc], acc[ti], 0, 0, 0);

        // hit mask (diagonal folded in); skip whole epilogue if wave-empty
        unsigned hm = 0u;
#pragma unroll
        for (int ti = 0; ti < 4; ++ti)
#pragma unroll
            for (int i = 0; i < 4; ++i) {
                bool hit = acc[ti][i] >= vt;
                if (!nodiag) {
                    int r = r0 + ti * 16 + quad * 4 + i;
                    hit = hit && (r != cj);
                }
                hm |= hit ? (1u << (ti * 4 + i)) : 0u;
            }

        if (__any(hm != 0u)) {
#pragma unroll
            for (int ti = 0; ti < 4; ++ti)
#pragma unroll
                for (int i = 0; i < 4; ++i) {
                    if (hm & (1u << (ti * 4 + i))) {
                        int r = r0 + ti * 16 + quad * 4 + i;
                        unsigned rc = (unsigned)r * (unsigned)NB + (unsigned)cj;
                        unsigned p = atomicAdd(&lcnt, 1u);
                        if (p < LCAP) {
                            lbuf[p] = rc;
                        } else {
                            unsigned g = atomicAdd(&ctrl[0], 1u);
                            if (g < CAP) cidx[g] = rc;
                        }
                    }
                }
        }

        // rotate pipeline (full unroll -> register renames, no copies)
        if (q < 6) {
            b0[0] = b1[0]; b0[1] = b1[1];
            b1[0] = b2[0]; b1[1] = b2[1];
        } else if (q == 6) {
            b0[0] = b1[0]; b0[1] = b1[1];
        }
    }

    __syncthreads();
    unsigned n = lcnt; if (n > LCAP) n = LCAP;
    if (tid == 0 && n) gbase = atomicAdd(&ctrl[0], n);
    __syncthreads();
    for (unsigned i = tid; i < n; i += 256u) {
        unsigned p = gbase + i;
        if (p < CAP) cidx[p] = lbuf[i];
    }
}

// ---------------------------------------------------------------------------
// K4b: refine — one wave per candidate (grid-stride): 64 coalesced f64
// loads, product, butterfly reduce (deterministic; 1e-15 << 1e-5 gaps).
// ---------------------------------------------------------------------------
__global__ __launch_bounds__(256) void refine_kernel(
    const unsigned* __restrict__ ctrl, const unsigned* __restrict__ cidx,
    const double* __restrict__ Xs64, const double* __restrict__ Xo64,
    double* __restrict__ cval)
{
    unsigned M = ctrl[0];
    if (M > CAP) M = CAP;
    unsigned nw = gridDim.x * 4u;
    int lane = threadIdx.x & 63;
    for (unsigned w = blockIdx.x * 4u + (threadIdx.x >> 6); w < M; w += nw) {
        unsigned id = cidx[w];
        unsigned r = id >> 13, c = id & (NB - 1);
        double p = Xs64[(size_t)r * HID + lane] * Xo64[(size_t)c * HID + lane];
#pragma unroll
        for (int s = 32; s > 0; s >>= 1) p += __shfl_xor(p, s);
        if (lane == 0) cval[w] = (r == c) ? -1.0 : p;
    }
}

// ---------------------------------------------------------------------------
// K5a: rank-by-counting, 4 candidates per thread with stride-256 ownership
// inside a 1024-wide i-tile (coalesced loads/atomics). Inner loop reads
// each LDS (ev,ei) pair once for 4 composite compares. Key: value desc,
// index asc (jax top_k tie-break). Grid-stride i-tiles x j-slices.
// ---------------------------------------------------------------------------
__global__ __launch_bounds__(256) void rank_count(
    const unsigned* __restrict__ ctrl,
    const double* __restrict__ cval, const unsigned* __restrict__ cidx,
    unsigned* __restrict__ rank)
{
    unsigned M = ctrl[0];
    if (M > CAP) M = CAP;

    unsigned slice = blockIdx.y;
    unsigned jbeg = (unsigned)(((unsigned long long)slice * M) / JSLICES);
    unsigned jend = (unsigned)(((unsigned long long)(slice + 1) * M) / JSLICES);

    __shared__ double  lv[256];
    __shared__ unsigned li[256];

    for (unsigned itile = blockIdx.x; itile * 1024u < M; itile += gridDim.x) {
        unsigned i0 = itile * 1024u + threadIdx.x;   // + k*256 per slot
        double v[4];
        unsigned id[4];
        unsigned cnt[4] = {0, 0, 0, 0};
#pragma unroll
        for (int k = 0; k < 4; ++k) {
            unsigned idx = i0 + (unsigned)k * 256u;
            bool a = idx < M;
            v[k]  = a ? cval[idx] : 0.0;
            id[k] = a ? cidx[idx] : 0u;
        }

        for (unsigned base = jbeg; base < jend; base += 256u) {
            unsigned j = base + threadIdx.x;
            if (j < jend) { lv[threadIdx.x] = cval[j]; li[threadIdx.x] = cidx[j]; }
            __syncthreads();
            unsigned lim = jend - base; if (lim > 256u) lim = 256u;
            for (unsigned e = 0; e < lim; ++e) {
                double ev = lv[e];
                unsigned ei = li[e];
#pragma unroll
                for (int k = 0; k < 4; ++k)
                    cnt[k] += (ev > v[k]) || (ev == v[k] && ei < id[k]);
            }
            __syncthreads();
        }
#pragma unroll
        for (int k = 0; k < 4; ++k) {
            unsigned idx = i0 + (unsigned)k * 256u;
            if (idx < M && cnt[k]) atomicAdd(&rank[idx], cnt[k]);
        }
    }
}

// ---------------------------------------------------------------------------
// K5b: scatter rank<TOPK candidates into sorted arrays AND build the NMS
// union boxes + 0.7*area in the same pass.
// ---------------------------------------------------------------------------
__global__ __launch_bounds__(256) void rank_scatter_prep(
    const unsigned* __restrict__ ctrl,
    const double* __restrict__ cval, const unsigned* __restrict__ cidx,
    const unsigned* __restrict__ rank, const float* __restrict__ rois,
    double* __restrict__ sval, unsigned* __restrict__ sidx,
    double* __restrict__ ub)
{
    unsigned M = ctrl[0];
    if (M > CAP) M = CAP;
    unsigned stride = gridDim.x * 256u;
    for (unsigned t = blockIdx.x * 256u + threadIdx.x; t < M; t += stride) {
        unsigned rk = rank[t];
        if (rk < TOPK) {
            unsigned id = cidx[t];
            sval[rk] = cval[t];
            sidx[rk] = id;
            unsigned s = id >> 13, o = id & (NB - 1);
            const float* bs = rois + (size_t)s * 5;
            const float* bo = rois + (size_t)o * 5;
            double x1 = fmin((double)bs[1], (double)bo[1]);
            double y1 = fmin((double)bs[2], (double)bo[2]);
            double x2 = fmax((double)bs[3], (double)bo[3]);
            double y2 = fmax((double)bs[4], (double)bo[4]);
            double area = (x2 - x1) * (y2 - y1);
            double* u = ub + (size_t)rk * 5;
            u[0] = x1; u[1] = y1; u[2] = x2; u[3] = y2; u[4] = 0.7 * area;
        }
    }
}

// ---------------------------------------------------------------------------
// K7: suppressed[j] = OR_{i<j} (iou > 0.7), chunk-parallel & branchless.
// Block = 256 j's x 64-i chunk. Division-free test; plain store (benign).
// ---------------------------------------------------------------------------
__global__ __launch_bounds__(256) void nms_kernel(
    const double* __restrict__ ub, unsigned* sup)
{
    int jb = blockIdx.x;              // j-tile: 256 j's
    int ic = blockIdx.y;              // i-chunk: 64 i's
    int ibase = ic * NMS_ICH;
    if (ibase >= TOPK) return;
    if (ibase >= jb * 256 + 255) return;   // no i < j pairs in this block

    __shared__ double L[NMS_ICH][5];
    int tid = threadIdx.x;
    int icount = TOPK - ibase; if (icount > NMS_ICH) icount = NMS_ICH;
    for (int q = tid; q < icount * 5; q += 256)
        L[q / 5][q % 5] = ub[(size_t)ibase * 5 + q];
    __syncthreads();

    int j = jb * 256 + tid;
    if (j >= TOPK) return;
    int lim = j - ibase; if (lim > icount) lim = icount;  // i < j
    if (lim <= 0) return;

    const double* u = ub + (size_t)j * 5;
    double x1 = u[0], y1 = u[1], x2 = u[2], y2 = u[3], pa = u[4];
    bool flag = false;
    for (int e = 0; e < lim; ++e) {
        double ix1 = fmax(L[e][0], x1);
        double iy1 = fmax(L[e][1], y1);
        double ix2 = fmin(L[e][2], x2);
        double iy2 = fmin(L[e][3], y2);
        double iw = ix2 - ix1; iw = iw > 0.0 ? iw : 0.0;
        double ih = iy2 - iy1; ih = ih > 0.0 ? ih : 0.0;
        flag |= (1.7 * (iw * ih) > pa + L[e][4] + 7e-9);
    }
    if (flag) sup[j] = 1u;
}

// ---------------------------------------------------------------------------
// K8: top-300 of where(sup,-1,score) = stable partition of the sorted list.
// Ballot-based wave scans: 3 barriers/chunk.
// ---------------------------------------------------------------------------
__global__ __launch_bounds__(1024) void finalize_kernel(
    const unsigned* __restrict__ sup, const double* __restrict__ sval,
    const unsigned* __restrict__ sidx, float* __restrict__ out)
{
    __shared__ unsigned wsum[16];
    __shared__ unsigned red[16];
    __shared__ unsigned bases[2];   // running {unsup, sup} counts
    __shared__ unsigned totalu_s;
    int tid  = threadIdx.x;
    int lane = tid & 63;
    int w    = tid >> 6;

    unsigned s = 0;
    for (int i = tid; i < TOPK; i += 1024) s += (sup[i] == 0u);
#pragma unroll
    for (int st = 32; st > 0; st >>= 1) s += __shfl_down(s, st);
    if (lane == 0) red[w] = s;
    __syncthreads();
    if (tid == 0) {
        unsigned tot = 0;
        for (int i = 0; i < 16; ++i) tot += red[i];
        totalu_s = tot; bases[0] = 0; bases[1] = 0;
    }
    __syncthreads();
    unsigned totalu = totalu_s;

    for (int c = 0; c < (TOPK + 1023) / 1024; ++c) {
        int idx = c * 1024 + tid;
        int valid = TOPK - c * 1024; if (valid > 1024) valid = 1024;
        unsigned f = (idx < TOPK && sup[idx] == 0u) ? 1u : 0u;
        unsigned long long m = __ballot(f != 0u);
        if (lane == 0) wsum[w] = (unsigned)__popcll(m);
        __syncthreads();
        unsigned wbase = 0, ctot = 0;
        for (int i = 0; i < 16; ++i) {
            unsigned v = wsum[i];
            if (i < w) wbase += v;
            ctot += v;
        }
        unsigned e = wbase + (unsigned)__popcll(m & ((1ull << lane) - 1ull));
        if (idx < TOPK) {
            unsigned pos = f ? (bases[0] + e)
                             : (totalu + bases[1] + (unsigned)tid - e);
            if (pos < POSTK) {
                unsigned id = sidx[idx];
                unsigned sb = id >> 13, ob = id & (NB - 1);
                out[2 * pos]     = (float)sb;
                out[2 * pos + 1] = (float)ob;
                double sg = f ? 1.0 / (1.0 + exp(-sval[idx])) : -1.0;
                out[2 * POSTK + pos] = (float)sg;
            }
        }
        __syncthreads();
        if (tid == 0) {
            bases[0] += ctot;
            bases[1] += (unsigned)valid - ctot;
        }
        __syncthreads();
    }
}

// ---------------------------------------------------------------------------
extern "C" void kernel_launch(void* const* d_in, const int* in_sizes, int n_in,
                              void* d_out, int out_size, void* d_ws, size_t ws_size,
                              hipStream_t stream)
{
    const float* rois = (const float*)d_in[0];
    const float* feat = (const float*)d_in[1];
    const float* W1s  = (const float*)d_in[2];
    const float* b1s  = (const float*)d_in[3];
    const float* W2s  = (const float*)d_in[4];
    const float* b2s  = (const float*)d_in[5];
    const float* W1o  = (const float*)d_in[6];
    const float* b1o  = (const float*)d_in[7];
    const float* W2o  = (const float*)d_in[8];
    const float* b2o  = (const float*)d_in[9];

    char* ws = (char*)d_ws;
    size_t off = 0;
    auto alloc = [&](size_t bytes) -> void* {
        off = (off + 255) & ~(size_t)255;
        void* p = ws + off;
        off += bytes;
        return p;
    };

    // zeroed region first
    unsigned* ghist = (unsigned*)alloc((size_t)BINS * 4);     // histogram
    unsigned* ctrl  = (unsigned*)alloc(256);                  // [0]=count [1]=bin [2]=thr [3]=election
    unsigned* sup   = (unsigned*)alloc((size_t)6144 * 4);     // suppression flags
    unsigned* rank  = (unsigned*)alloc((size_t)CAP * 4);      // candidate ranks
    size_t zero_bytes = off;

    double* Xs64 = (double*)alloc((size_t)NB * HID * 8);
    double* Xo64 = (double*)alloc((size_t)NB * HID * 8);
    unsigned short* Xsb = (unsigned short*)alloc((size_t)NB * HID * 2);
    unsigned short* Xob = (unsigned short*)alloc((size_t)NB * HID * 2);
    double* cval = (double*)alloc((size_t)CAP * 8);
    unsigned* cidx = (unsigned*)alloc((size_t)CAP * 4);
    double* svalv = (double*)alloc((size_t)TOPK * 8);
    unsigned* sidxv = (unsigned*)alloc((size_t)TOPK * 4);
    double* ub   = (double*)alloc((size_t)TOPK * 5 * 8);

    (void)hipMemsetAsync(d_ws, 0, zero_bytes, stream);

    mlp_kernel<<<NB / 16, 256, 0, stream>>>(feat, W1s, b1s, W2s, b2s,
                                            W1o, b1o, W2o, b2o,
                                            Xs64, Xo64, Xsb, Xob);
    mfma_hist<<<dim3(4, 64), 256, 0, stream>>>(Xsb, Xob, ghist, ctrl);
    mfma_filter<<<dim3(32, 64), 256, 0, stream>>>(Xsb, Xob, ctrl, cidx);
    refine_kernel<<<2048, 256, 0, stream>>>(ctrl, cidx, Xs64, Xo64, cval);
    rank_count<<<dim3(16, JSLICES), 256, 0, stream>>>(ctrl, cval, cidx, rank);
    rank_scatter_prep<<<512, 256, 0, stream>>>(ctrl, cval, cidx, rank, rois,
                                               svalv, sidxv, ub);
    nms_kernel<<<dim3((TOPK + 255) / 256, (TOPK + NMS_ICH - 1) / NMS_ICH), 256, 0, stream>>>(ub, sup);
    finalize_kernel<<<1, 1024, 0, stream>>>(sup, svalv, sidxv, (float*)d_out);
}

// Round 7
// 217.315 us; speedup vs baseline: 1.5074x; 1.0221x over previous
//
#include <hip/hip_runtime.h>
#include <math.h>

// Problem constants
#define NB    8192          // N
#define FEAT  255
#define HID   64
#define TOPK  6000
#define POSTK 300
#define BINS  8192          // 13-bit sortable-float key bins (sign+8exp+4mant)
#define BSHIFT 19           // 32-13
#define CAP   131072        // candidate buffer capacity
#define CAPLIM 16384        // R25: rank_count O(M^2), refine O(M); top-6000 coverage
                            // guaranteed by the bt<=bstar walk bound, not CAPLIM
#define SLACK 1             // bins below bstar (bf16-mfma vs f64 err 0.03 << bin 0.5)
#define TSEL  500           // sampled cnt_ge target (1/16 col sample: true>=6000 at ~6 sigma)
#define SAMPF 16            // sample factor (512 of 8192 cols)
#define JSLICES 128         // j-dimension parallelism for rank counting
#define LCAP  2048          // per-block LDS candidate buffer (overflow -> direct atomic)
#define NMS_ICH 64          // nms i-chunk per block

typedef __attribute__((ext_vector_type(8))) short bf16x8;
typedef __attribute__((ext_vector_type(4))) float f32x4;
typedef __attribute__((ext_vector_type(4))) double f64x4;

__device__ __forceinline__ unsigned binOf(float x) {
    unsigned u = __float_as_uint(x);
    u = (u & 0x80000000u) ? ~u : (u | 0x80000000u);   // sortable key (ascending)
    return u >> BSHIFT;
}

__device__ __forceinline__ unsigned short f2bf(float f) {   // RNE bf16 (finite inputs)
    unsigned u = __float_as_uint(f);
    return (unsigned short)((u + 0x7fffu + ((u >> 16) & 1u)) >> 16);
}

// ---------------------------------------------------------------------------
// K1 (R26): the two 255->64->64 MLPs via v_mfma_f64_16x16x4_f64. R21-R25 ran
// 512 blocks = 2 blocks/CU = 2 waves/SIMD — too few to hide the per-kstep
// L2 W-load latency under the dependent MFMA chain (persistent ~5x model
// gap while HBM-bound fills run at 84% peak => latency, not clocks). Now:
// block = (16 rows, ONE net), wave = one 16-col chain -> 1024 blocks =
// 4 blocks/CU = 4 waves/SIMD. Same MFMA count, same K-order per chain ->
// bit-identical X. net is block-uniform (scalar W base). Deterministic.
// ---------------------------------------------------------------------------
__global__ __launch_bounds__(256) void mlp_kernel(
    const float* __restrict__ feat,
    const float* __restrict__ W1s, const float* __restrict__ b1s,
    const float* __restrict__ W2s, const float* __restrict__ b2s,
    const float* __restrict__ W1o, const float* __restrict__ b1o,
    const float* __restrict__ W2o, const float* __restrict__ b2o,
    double* __restrict__ Xs64, double* __restrict__ Xo64,
    unsigned short* __restrict__ Xsb, unsigned short* __restrict__ Xob)
{
    __shared__ float  fl[16 * 258];       // feat tile, padded stride 258 (16.5 KB)
    __shared__ double hl[16][65];         // relu(h1) for this net (8.3 KB)

    int tid  = threadIdx.x;
    int lane = tid & 63;
    int w    = tid >> 6;
    int a16  = lane & 15;     // row (A) / col (B,D) within 16-tile
    int kq   = lane >> 4;     // k-quad 0..3
    int bx   = blockIdx.x;
    int net  = bx & 1;        // 0 = subject, 1 = object (block-uniform)
    int rbase = (bx >> 1) * 16;
    int c0   = w * 16 + a16;  // wave w owns cols [16w, 16w+16)

    // ---- stage feat tile: 16 rows x 255 f32, row-linear in global ----
    const float* fsrc = feat + (size_t)rbase * FEAT;
    for (int idx = tid; idx < 16 * FEAT; idx += 256) {
        int r = idx / FEAT;
        int k = idx - r * FEAT;
        fl[r * 258 + k] = fsrc[idx];
    }
    if (tid < 16) fl[tid * 258 + 255] = 0.0f;   // K-pad column
    __syncthreads();

    const float* W1 = net ? W1o : W1s;
    const float* B1 = net ? b1o : b1s;
    const float* W2 = net ? W2o : W2s;
    const float* B2 = net ? b2o : b2s;
    double*       X  = net ? Xo64 : Xs64;
    unsigned short* Xb = net ? Xob : Xsb;

    // ---- layer 1: K=255 -> 63 full ksteps + masked tail ----
    f64x4 acc0 = {0, 0, 0, 0};
#pragma unroll 4
    for (int ks = 0; ks < 63; ++ks) {
        int k = ks * 4 + kq;
        double av = (double)fl[a16 * 258 + k];
        double b0 = (double)W1[k * HID + c0];
        acc0 = __builtin_amdgcn_mfma_f64_16x16x4f64(av, b0, acc0, 0, 0, 0);
    }
    {   // tail kstep: k = 252+kq; kq==3 is the pad lane (A=0, B exec-masked)
        int k = 252 + kq;
        double av = (double)fl[a16 * 258 + k];
        double b0 = 0.0;
        if (k < FEAT) b0 = (double)W1[k * HID + c0];
        acc0 = __builtin_amdgcn_mfma_f64_16x16x4f64(av, b0, acc0, 0, 0, 0);
    }

    // bias + relu -> hl  (D: col = c0, row = kq*4 + i)
    {
        double bb0 = (double)B1[c0];
#pragma unroll
        for (int i = 0; i < 4; ++i) {
            int r = kq * 4 + i;
            double v0 = acc0[i] + bb0;
            hl[r][c0] = v0 > 0.0 ? v0 : 0.0;
        }
    }
    __syncthreads();

    // ---- layer 2: K=64 -> 16 ksteps ----
    f64x4 x0 = {0, 0, 0, 0};
#pragma unroll 4
    for (int ks = 0; ks < 16; ++ks) {
        int k = ks * 4 + kq;
        double av = hl[a16][k];
        double b0 = (double)W2[k * HID + c0];
        x0 = __builtin_amdgcn_mfma_f64_16x16x4f64(av, b0, x0, 0, 0, 0);
    }

    // bias + store f64 and bf16 views
    {
        double bb0 = (double)B2[c0];
#pragma unroll
        for (int i = 0; i < 4; ++i) {
            int r = kq * 4 + i;
            double v0 = x0[i] + bb0;
            size_t o0 = (size_t)(rbase + r) * HID + c0;
            X[o0] = v0;
            Xb[o0] = f2bf((float)v0);
        }
    }
}

// ---------------------------------------------------------------------------
// K2: histogram over a 1/16 column sample (cols 0..511) with fused
// threshold selection via last-block election on ctrl[3] (R23, verified:
// the fused tail is O(BINS)=8K, small enough to serialize).
// ---------------------------------------------------------------------------
__global__ __launch_bounds__(256) void mfma_hist(
    const unsigned short* __restrict__ Xsb, const unsigned short* __restrict__ Xob,
    unsigned* __restrict__ ghist, unsigned* __restrict__ ctrl)
{
    __shared__ unsigned hist[BINS];   // 32 KB (reused as staged ghist by winner)
    __shared__ unsigned csum[256];
    __shared__ bool win_s;
    int tid = threadIdx.x;
    for (int i = tid; i < BINS; i += 256) hist[i] = 0u;
    __syncthreads();

    int lane = tid & 63;
    int wave = tid >> 6;
    int quad = lane >> 4;
    int l16  = lane & 15;
    int r0 = blockIdx.y * 128 + (wave >> 1) * 64;
    int c0 = blockIdx.x * 128 + (wave & 1) * 64;   // gridDim.x = 4 -> cols 0..511

    f32x4 acc[4][4];
    bf16x8 afr[2][4], bfr[2][4];
#pragma unroll
    for (int kc = 0; kc < 2; ++kc)
#pragma unroll
        for (int t = 0; t < 4; ++t) {
            afr[kc][t] = *(const bf16x8*)(Xsb + (size_t)(r0 + t * 16 + l16) * HID + kc * 32 + quad * 8);
            bfr[kc][t] = *(const bf16x8*)(Xob + (size_t)(c0 + t * 16 + l16) * HID + kc * 32 + quad * 8);
        }
#pragma unroll
    for (int ti = 0; ti < 4; ++ti)
#pragma unroll
        for (int tj = 0; tj < 4; ++tj) acc[ti][tj] = (f32x4){0, 0, 0, 0};
#pragma unroll
    for (int kc = 0; kc < 2; ++kc)
#pragma unroll
        for (int ti = 0; ti < 4; ++ti)
#pragma unroll
            for (int tj = 0; tj < 4; ++tj)
                acc[ti][tj] = __builtin_amdgcn_mfma_f32_16x16x32_bf16(
                    afr[kc][ti], bfr[kc][tj], acc[ti][tj], 0, 0, 0);

#pragma unroll
    for (int ti = 0; ti < 4; ++ti)
#pragma unroll
        for (int tj = 0; tj < 4; ++tj)
#pragma unroll
            for (int i = 0; i < 4; ++i) {
                int r = r0 + ti * 16 + quad * 4 + i;
                int c = c0 + tj * 16 + l16;
                float v = acc[ti][tj][i];
                if (v > 0.0f && r != c)
                    atomicAdd(&hist[binOf(v)], 1u);
            }

    __syncthreads();
    for (int i = tid; i < BINS; i += 256) {
        unsigned h = hist[i];
        if (h) atomicAdd(&ghist[i], h);
    }

    // ---- last-block election: winner computes the threshold ----
    __syncthreads();
    if (tid == 0) {
        __threadfence();
        unsigned done = atomicAdd(&ctrl[3], 1u);
        win_s = (done == gridDim.x * gridDim.y - 1u);
    }
    __syncthreads();
    if (!win_s) return;

    for (int i = tid; i < BINS; i += 256)
        hist[i] = __hip_atomic_load(&ghist[i], __ATOMIC_RELAXED, __HIP_MEMORY_SCOPE_AGENT);
    __syncthreads();

    int base = tid * (BINS / 256);
    unsigned s = 0;
    for (int i = 0; i < BINS / 256; ++i) s += hist[base + i];
    csum[tid] = s;
    __syncthreads();
    if (tid == 0) {                       // suffix sums of chunk totals
        unsigned run = 0;
        for (int c = 255; c >= 0; --c) { run += csum[c]; csum[c] = run; }
    }
    __syncthreads();

    unsigned above = (tid == 255) ? 0u : csum[tid + 1];  // cnt_ge[chunk end]
    unsigned prev = above;
    for (int b = base + BINS / 256 - 1; b >= base; --b) {
        unsigned cur = prev + hist[b];
        if (cur >= TSEL && prev < TSEL) {
            unsigned bstar = (unsigned)b;
            unsigned bt = bstar >= SLACK ? bstar - SLACK : 0;
            unsigned cnt = cur;
            for (unsigned bb = bstar; bb-- > bt;) cnt += hist[bb];
            while ((unsigned)SAMPF * cnt > CAPLIM && bt < bstar) { cnt -= hist[bt]; bt++; }
            ctrl[1] = bt;
            unsigned key = bt << BSHIFT;
            unsigned fbits;
            if (key == 0u) fbits = 0xff800000u;               // -inf: all pass
            else fbits = (key & 0x80000000u) ? (key ^ 0x80000000u) : ~key;
            ctrl[2] = fbits;
            break;
        }
        prev = cur;
    }
}

// ---------------------------------------------------------------------------
// K4: filter pass, 128x256 tile/block, chunked 16-AGPR accumulator, dist-2
// B prefetch, hit-mask fast path (skip atomic epilogue when wave-empty).
// Same candidate set; chunk order free. (R3-verified structure.)
// ---------------------------------------------------------------------------
__global__ __launch_bounds__(256) void mfma_filter(
    const unsigned short* __restrict__ Xsb, const unsigned short* __restrict__ Xob,
    unsigned* __restrict__ ctrl, unsigned* __restrict__ cidx)
{
    __shared__ unsigned lcnt;
    __shared__ unsigned gbase;
    __shared__ unsigned lbuf[LCAP];   // 8 KB
    float vt = __uint_as_float(ctrl[2]);
    int tid = threadIdx.x;
    if (tid == 0) lcnt = 0;

    int lane = tid & 63;
    int wave = tid >> 6;
    int quad = lane >> 4;
    int l16  = lane & 15;
    int r0 = blockIdx.y * 128 + (wave >> 1) * 64;
    int cb = blockIdx.x * 256 + (wave & 1) * 64;

    // A fragments: loaded once, reused across all 8 column chunks
    bf16x8 afr[2][4];
#pragma unroll
    for (int kc = 0; kc < 2; ++kc)
#pragma unroll
        for (int t = 0; t < 4; ++t)
            afr[kc][t] = *(const bf16x8*)(Xsb + (size_t)(r0 + t * 16 + l16) * HID + kc * 32 + quad * 8);

    // prefetch chunk 0 and chunk 1's B fragments (pipeline stages b0,b1)
    bf16x8 b0[2], b1[2];
    {
        int col0 = cb + l16;           // q=0: ct=0, tj=0
        int col1 = cb + 16 + l16;      // q=1: ct=0, tj=1
#pragma unroll
        for (int kc = 0; kc < 2; ++kc) {
            b0[kc] = *(const bf16x8*)(Xob + (size_t)col0 * HID + kc * 32 + quad * 8);
            b1[kc] = *(const bf16x8*)(Xob + (size_t)col1 * HID + kc * 32 + quad * 8);
        }
    }

    __syncthreads();   // lcnt=0 visible

#pragma unroll
    for (int q = 0; q < 8; ++q) {
        int ct = q >> 2, tj = q & 3;
        int c0 = cb + ct * 128;
        int cj = c0 + tj * 16 + l16;
        bool nodiag = (r0 != c0);

        // prefetch chunk q+2's B fragments
        bf16x8 b2[2];
        if (q < 6) {
            int q2 = q + 2;
            int col2 = cb + (q2 >> 2) * 128 + (q2 & 3) * 16 + l16;
#pragma unroll
            for (int kc = 0; kc < 2; ++kc)
                b2[kc] = *(const bf16x8*)(Xob + (size_t)col2 * HID + kc * 32 + quad * 8);
        }

        f32x4 acc[4];
#pragma unroll
        for (int ti = 0; ti < 4; ++ti) acc[ti] = (f32x4){0, 0, 0, 0};
#pragma unroll
        for (int kc = 0; kc < 2; ++kc)
#pragma unroll
            for (int ti = 0; ti < 4; ++ti)
                acc[ti] = __builtin_amdgcn_mfma_f32_16x16x32_bf16(
                    afr[kc][ti], b0[kc], acc[ti], 0, 0, 0);

        // hit mask (diagonal folded in); skip whole epilogue if wave-empty
        unsigned hm = 0u;
#pragma unroll
        for (int ti = 0; ti < 4; ++ti)
#pragma unroll
            for (int i = 0; i < 4; ++i) {
                bool hit = acc[ti][i] >= vt;
                if (!nodiag) {
                    int r = r0 + ti * 16 + quad * 4 + i;
                    hit = hit && (r != cj);
                }
                hm |= hit ? (1u << (ti * 4 + i)) : 0u;
            }

        if (__any(hm != 0u)) {
#pragma unroll
            for (int ti = 0; ti < 4; ++ti)
#pragma unroll
                for (int i = 0; i < 4; ++i) {
                    if (hm & (1u << (ti * 4 + i))) {
                        int r = r0 + ti * 16 + quad * 4 + i;
                        unsigned rc = (unsigned)r * (unsigned)NB + (unsigned)cj;
                        unsigned p = atomicAdd(&lcnt, 1u);
                        if (p < LCAP) {
                            lbuf[p] = rc;
                        } else {
                            unsigned g = atomicAdd(&ctrl[0], 1u);
                            if (g < CAP) cidx[g] = rc;
                        }
                    }
                }
        }

        // rotate pipeline (full unroll -> register renames, no copies)
        if (q < 6) {
            b0[0] = b1[0]; b0[1] = b1[1];
            b1[0] = b2[0]; b1[1] = b2[1];
        } else if (q == 6) {
            b0[0] = b1[0]; b0[1] = b1[1];
        }
    }

    __syncthreads();
    unsigned n = lcnt; if (n > LCAP) n = LCAP;
    if (tid == 0 && n) gbase = atomicAdd(&ctrl[0], n);
    __syncthreads();
    for (unsigned i = tid; i < n; i += 256u) {
        unsigned p = gbase + i;
        if (p < CAP) cidx[p] = lbuf[i];
    }
}

// ---------------------------------------------------------------------------
// K4b: refine — one wave per candidate (grid-stride): 64 coalesced f64
// loads, product, butterfly reduce (deterministic; 1e-15 << 1e-5 gaps).
// ---------------------------------------------------------------------------
__global__ __launch_bounds__(256) void refine_kernel(
    const unsigned* __restrict__ ctrl, const unsigned* __restrict__ cidx,
    const double* __restrict__ Xs64, const double* __restrict__ Xo64,
    double* __restrict__ cval)
{
    unsigned M = ctrl[0];
    if (M > CAP) M = CAP;
    unsigned nw = gridDim.x * 4u;
    int lane = threadIdx.x & 63;
    for (unsigned w = blockIdx.x * 4u + (threadIdx.x >> 6); w < M; w += nw) {
        unsigned id = cidx[w];
        unsigned r = id >> 13, c = id & (NB - 1);
        double p = Xs64[(size_t)r * HID + lane] * Xo64[(size_t)c * HID + lane];
#pragma unroll
        for (int s = 32; s > 0; s >>= 1) p += __shfl_xor(p, s);
        if (lane == 0) cval[w] = (r == c) ? -1.0 : p;
    }
}

// ---------------------------------------------------------------------------
// K5a: rank-by-counting, 4 candidates per thread with stride-256 ownership
// inside a 1024-wide i-tile (coalesced loads/atomics). Inner loop reads
// each LDS (ev,ei) pair once for 4 composite compares. Key: value desc,
// index asc (jax top_k tie-break). Grid-stride i-tiles x j-slices.
// ---------------------------------------------------------------------------
__global__ __launch_bounds__(256) void rank_count(
    const unsigned* __restrict__ ctrl,
    const double* __restrict__ cval, const unsigned* __restrict__ cidx,
    unsigned* __restrict__ rank)
{
    unsigned M = ctrl[0];
    if (M > CAP) M = CAP;

    unsigned slice = blockIdx.y;
    unsigned jbeg = (unsigned)(((unsigned long long)slice * M) / JSLICES);
    unsigned jend = (unsigned)(((unsigned long long)(slice + 1) * M) / JSLICES);

    __shared__ double  lv[256];
    __shared__ unsigned li[256];

    for (unsigned itile = blockIdx.x; itile * 1024u < M; itile += gridDim.x) {
        unsigned i0 = itile * 1024u + threadIdx.x;   // + k*256 per slot
        double v[4];
        unsigned id[4];
        unsigned cnt[4] = {0, 0, 0, 0};
#pragma unroll
        for (int k = 0; k < 4; ++k) {
            unsigned idx = i0 + (unsigned)k * 256u;
            bool a = idx < M;
            v[k]  = a ? cval[idx] : 0.0;
            id[k] = a ? cidx[idx] : 0u;
        }

        for (unsigned base = jbeg; base < jend; base += 256u) {
            unsigned j = base + threadIdx.x;
            if (j < jend) { lv[threadIdx.x] = cval[j]; li[threadIdx.x] = cidx[j]; }
            __syncthreads();
            unsigned lim = jend - base; if (lim > 256u) lim = 256u;
            for (unsigned e = 0; e < lim; ++e) {
                double ev = lv[e];
                unsigned ei = li[e];
#pragma unroll
                for (int k = 0; k < 4; ++k)
                    cnt[k] += (ev > v[k]) || (ev == v[k] && ei < id[k]);
            }
            __syncthreads();
        }
#pragma unroll
        for (int k = 0; k < 4; ++k) {
            unsigned idx = i0 + (unsigned)k * 256u;
            if (idx < M && cnt[k]) atomicAdd(&rank[idx], cnt[k]);
        }
    }
}

// ---------------------------------------------------------------------------
// K5b: scatter rank<TOPK candidates into sorted arrays AND build the NMS
// union boxes + 0.7*area in the same pass.
// ---------------------------------------------------------------------------
__global__ __launch_bounds__(256) void rank_scatter_prep(
    const unsigned* __restrict__ ctrl,
    const double* __restrict__ cval, const unsigned* __restrict__ cidx,
    const unsigned* __restrict__ rank, const float* __restrict__ rois,
    double* __restrict__ sval, unsigned* __restrict__ sidx,
    double* __restrict__ ub)
{
    unsigned M = ctrl[0];
    if (M > CAP) M = CAP;
    unsigned stride = gridDim.x * 256u;
    for (unsigned t = blockIdx.x * 256u + threadIdx.x; t < M; t += stride) {
        unsigned rk = rank[t];
        if (rk < TOPK) {
            unsigned id = cidx[t];
            sval[rk] = cval[t];
            sidx[rk] = id;
            unsigned s = id >> 13, o = id & (NB - 1);
            const float* bs = rois + (size_t)s * 5;
            const float* bo = rois + (size_t)o * 5;
            double x1 = fmin((double)bs[1], (double)bo[1]);
            double y1 = fmin((double)bs[2], (double)bo[2]);
            double x2 = fmax((double)bs[3], (double)bo[3]);
            double y2 = fmax((double)bs[4], (double)bo[4]);
            double area = (x2 - x1) * (y2 - y1);
            double* u = ub + (size_t)rk * 5;
            u[0] = x1; u[1] = y1; u[2] = x2; u[3] = y2; u[4] = 0.7 * area;
        }
    }
}

// ---------------------------------------------------------------------------
// K7: suppressed[j] = OR_{i<j} (iou > 0.7), chunk-parallel & branchless.
// Block = 256 j's x 64-i chunk. Division-free test; plain store (benign).
// ---------------------------------------------------------------------------
__global__ __launch_bounds__(256) void nms_kernel(
    const double* __restrict__ ub, unsigned* sup)
{
    int jb = blockIdx.x;              // j-tile: 256 j's
    int ic = blockIdx.y;              // i-chunk: 64 i's
    int ibase = ic * NMS_ICH;
    if (ibase >= TOPK) return;
    if (ibase >= jb * 256 + 255) return;   // no i < j pairs in this block

    __shared__ double L[NMS_ICH][5];
    int tid = threadIdx.x;
    int icount = TOPK - ibase; if (icount > NMS_ICH) icount = NMS_ICH;
    for (int q = tid; q < icount * 5; q += 256)
        L[q / 5][q % 5] = ub[(size_t)ibase * 5 + q];
    __syncthreads();

    int j = jb * 256 + tid;
    if (j >= TOPK) return;
    int lim = j - ibase; if (lim > icount) lim = icount;  // i < j
    if (lim <= 0) return;

    const double* u = ub + (size_t)j * 5;
    double x1 = u[0], y1 = u[1], x2 = u[2], y2 = u[3], pa = u[4];
    bool flag = false;
    for (int e = 0; e < lim; ++e) {
        double ix1 = fmax(L[e][0], x1);
        double iy1 = fmax(L[e][1], y1);
        double ix2 = fmin(L[e][2], x2);
        double iy2 = fmin(L[e][3], y2);
        double iw = ix2 - ix1; iw = iw > 0.0 ? iw : 0.0;
        double ih = iy2 - iy1; ih = ih > 0.0 ? ih : 0.0;
        flag |= (1.7 * (iw * ih) > pa + L[e][4] + 7e-9);
    }
    if (flag) sup[j] = 1u;
}

// ---------------------------------------------------------------------------
// K8 (R26): top-300 of where(sup,-1,score) = stable partition. Was 1 block
// (the R24 anti-pattern: single-block serialization costs 10-30x dispatch
// overhead). Now 6 blocks: each redundantly scans the whole 24 KB sup[]
// (L2-hot) to compute totalu + its own prefix bases, then ballot-scatters
// only its own 1024-chunk. Identical output positions by prefix math.
// ---------------------------------------------------------------------------
__global__ __launch_bounds__(1024) void finalize_kernel(
    const unsigned* __restrict__ sup, const double* __restrict__ sval,
    const unsigned* __restrict__ sidx, float* __restrict__ out)
{
    __shared__ unsigned wsum[16];
    __shared__ unsigned red2[16][2];
    __shared__ unsigned totalu_s, ubase_s;
    int tid  = threadIdx.x;
    int lane = tid & 63;
    int w    = tid >> 6;
    int mybase = blockIdx.x * 1024;

    // full-array scan: total unsuppressed + unsuppressed before my chunk
    unsigned tot = 0, bef = 0;
    for (int i = tid; i < TOPK; i += 1024) {
        unsigned f = (sup[i] == 0u) ? 1u : 0u;
        tot += f;
        bef += (i < mybase) ? f : 0u;
    }
#pragma unroll
    for (int st = 32; st > 0; st >>= 1) {
        tot += __shfl_down(tot, st);
        bef += __shfl_down(bef, st);
    }
    if (lane == 0) { red2[w][0] = tot; red2[w][1] = bef; }
    __syncthreads();
    if (tid == 0) {
        unsigned t = 0, b = 0;
        for (int i = 0; i < 16; ++i) { t += red2[i][0]; b += red2[i][1]; }
        totalu_s = t; ubase_s = b;
    }
    __syncthreads();
    unsigned totalu = totalu_s;
    unsigned ubase  = ubase_s;
    unsigned sbase  = (unsigned)mybase - ubase;   // suppressed before my chunk

    int idx = mybase + tid;
    unsigned f = (idx < TOPK && sup[idx] == 0u) ? 1u : 0u;
    unsigned long long m = __ballot(f != 0u);
    if (lane == 0) wsum[w] = (unsigned)__popcll(m);
    __syncthreads();
    unsigned wbase = 0;
#pragma unroll
    for (int i = 0; i < 16; ++i)
        if (i < w) wbase += wsum[i];
    unsigned e = wbase + (unsigned)__popcll(m & ((1ull << lane) - 1ull));
    if (idx < TOPK) {
        unsigned pos = f ? (ubase + e)
                         : (totalu + sbase + (unsigned)tid - e);
        if (pos < POSTK) {
            unsigned id = sidx[idx];
            unsigned sb = id >> 13, ob = id & (NB - 1);
            out[2 * pos]     = (float)sb;
            out[2 * pos + 1] = (float)ob;
            double sg = f ? 1.0 / (1.0 + exp(-sval[idx])) : -1.0;
            out[2 * POSTK + pos] = (float)sg;
        }
    }
}

// ---------------------------------------------------------------------------
extern "C" void kernel_launch(void* const* d_in, const int* in_sizes, int n_in,
                              void* d_out, int out_size, void* d_ws, size_t ws_size,
                              hipStream_t stream)
{
    const float* rois = (const float*)d_in[0];
    const float* feat = (const float*)d_in[1];
    const float* W1s  = (const float*)d_in[2];
    const float* b1s  = (const float*)d_in[3];
    const float* W2s  = (const float*)d_in[4];
    const float* b2s  = (const float*)d_in[5];
    const float* W1o  = (const float*)d_in[6];
    const float* b1o  = (const float*)d_in[7];
    const float* W2o  = (const float*)d_in[8];
    const float* b2o  = (const float*)d_in[9];

    char* ws = (char*)d_ws;
    size_t off = 0;
    auto alloc = [&](size_t bytes) -> void* {
        off = (off + 255) & ~(size_t)255;
        void* p = ws + off;
        off += bytes;
        return p;
    };

    // zeroed region first
    unsigned* ghist = (unsigned*)alloc((size_t)BINS * 4);     // histogram
    unsigned* ctrl  = (unsigned*)alloc(256);                  // [0]=count [1]=bin [2]=thr [3]=election
    unsigned* sup   = (unsigned*)alloc((size_t)6144 * 4);     // suppression flags
    unsigned* rank  = (unsigned*)alloc((size_t)CAP * 4);      // candidate ranks
    size_t zero_bytes = off;

    double* Xs64 = (double*)alloc((size_t)NB * HID * 8);
    double* Xo64 = (double*)alloc((size_t)NB * HID * 8);
    unsigned short* Xsb = (unsigned short*)alloc((size_t)NB * HID * 2);
    unsigned short* Xob = (unsigned short*)alloc((size_t)NB * HID * 2);
    double* cval = (double*)alloc((size_t)CAP * 8);
    unsigned* cidx = (unsigned*)alloc((size_t)CAP * 4);
    double* svalv = (double*)alloc((size_t)TOPK * 8);
    unsigned* sidxv = (unsigned*)alloc((size_t)TOPK * 4);
    double* ub   = (double*)alloc((size_t)TOPK * 5 * 8);

    (void)hipMemsetAsync(d_ws, 0, zero_bytes, stream);

    mlp_kernel<<<(NB / 16) * 2, 256, 0, stream>>>(feat, W1s, b1s, W2s, b2s,
                                                  W1o, b1o, W2o, b2o,
                                                  Xs64, Xo64, Xsb, Xob);
    mfma_hist<<<dim3(4, 64), 256, 0, stream>>>(Xsb, Xob, ghist, ctrl);
    mfma_filter<<<dim3(32, 64), 256, 0, stream>>>(Xsb, Xob, ctrl, cidx);
    refine_kernel<<<2048, 256, 0, stream>>>(ctrl, cidx, Xs64, Xo64, cval);
    rank_count<<<dim3(16, JSLICES), 256, 0, stream>>>(ctrl, cval, cidx, rank);
    rank_scatter_prep<<<512, 256, 0, stream>>>(ctrl, cval, cidx, rank, rois,
                                               svalv, sidxv, ub);
    nms_kernel<<<dim3((TOPK + 255) / 256, (TOPK + NMS_ICH - 1) / NMS_ICH), 256, 0, stream>>>(ub, sup);
    finalize_kernel<<<(TOPK + 1023) / 1024, 1024, 0, stream>>>(sup, svalv, sidxv, (float*)d_out);
}